// Round 1
// baseline (751.260 us; speedup 1.0000x reference)
//
#include <hip/hip_runtime.h>

#define BB 8
#define MM 4096
#define EE 1024
#define DD 128
#define NCAT 64
#define CAP 384   // max members per edge; Binomial(4096,0.05) mean 205, std 14 -> 384 is >12 sigma

// ---------------------------------------------------------------------------
// K1: build per-(b,e) member lists from the binary incidence matrix.
// Coalesced float4 read of inc (B,M,E); ~5% nonzeros -> atomicAdd slot + store m.
// ---------------------------------------------------------------------------
__global__ __launch_bounds__(256) void k_build(const float* __restrict__ inc,
                                               int* __restrict__ cnt,
                                               unsigned short* __restrict__ lst) {
    int idx = blockIdx.x * 256 + threadIdx.x;          // one float4 per thread
    const float4 v = reinterpret_cast<const float4*>(inc)[idx];
    int flat = idx << 2;                               // element index, e fastest
    int e0 = flat & (EE - 1);
    int m  = (flat >> 10) & (MM - 1);
    int b  = flat >> 22;                               // 10 (E) + 12 (M)
    float vv[4] = {v.x, v.y, v.z, v.w};
    int be_base = b * EE + e0;
#pragma unroll
    for (int j = 0; j < 4; ++j) {
        if (vv[j] != 0.0f) {
            int be = be_base + j;
            int slot = atomicAdd(&cnt[be], 1);
            if (slot < CAP) lst[be * CAP + slot] = (unsigned short)m;
        }
    }
}

// ---------------------------------------------------------------------------
// K2: agg[b,e,:] = sum over member nodes of node_feats[b,m,:]
// One block (128 threads = thread per d) per (b,e).  b = blk&7 -> blocks of
// batch b land on XCD b (round-robin dispatch), so nf[b] (2 MB) stays in that
// XCD's 4 MB L2 and the gather is L2-resident.
// ---------------------------------------------------------------------------
__global__ __launch_bounds__(128) void k_agg(const float* __restrict__ nf,
                                             const int* __restrict__ cnt,
                                             const unsigned short* __restrict__ lst,
                                             float* __restrict__ agg) {
    __shared__ unsigned short ll[CAP];
    int blk = blockIdx.x;
    int b = blk & 7;
    int e = blk >> 3;
    int be = b * EE + e;
    int n = cnt[be];
    if (n > CAP) n = CAP;
    const unsigned short* lp = lst + be * CAP;
    for (int i = threadIdx.x; i < n; i += 128) ll[i] = lp[i];
    __syncthreads();
    int d = threadIdx.x;
    const float* nfb = nf + ((long)b * MM * DD) + d;
    float acc = 0.0f;
    int i = 0;
    for (; i + 4 <= n; i += 4) {
        uint2 w = *reinterpret_cast<const uint2*>(&ll[i]);
        int m0 = w.x & 0xffff, m1 = w.x >> 16;
        int m2 = w.y & 0xffff, m3 = w.y >> 16;
        float x0 = nfb[m0 * DD], x1 = nfb[m1 * DD];
        float x2 = nfb[m2 * DD], x3 = nfb[m3 * DD];
        acc += x0; acc += x1; acc += x2; acc += x3;
    }
    for (; i < n; ++i) acc += nfb[(int)ll[i] * DD];
    agg[(long)be * DD + d] = acc;
}

// ---------------------------------------------------------------------------
// K3/K5: Y[r,:] = X[r,:] @ W^T for X (8192 x 128), W (128 x 128), fp32.
// W stored transposed in LDS with stride 129 (conflict-free), X tile rows read
// as broadcast float4.  Each block: 16 rows, 256 threads (j = tid&127,
// half = tid>>7 owns 8 rows).  WITH_A additionally computes
// a[r] = Y[r,:] . att  (wave shfl reduction).
// ---------------------------------------------------------------------------
template <bool WITH_A>
__global__ __launch_bounds__(256) void k_rowgemm(const float* __restrict__ X,
                                                 const float* __restrict__ W,
                                                 float* __restrict__ Y,
                                                 const float* __restrict__ att,
                                                 float* __restrict__ a_out) {
    __shared__ float Wt[128][129];   // Wt[k][j] = W[j][k]
    __shared__ float xt[16][128];
    __shared__ float ared[4][8];
    int tid = threadIdx.x;
    for (int t = tid; t < 128 * 128; t += 256) {
        int j = t >> 7, k = t & 127;
        Wt[k][j] = W[t];
    }
    int e0 = blockIdx.x * 16;
    for (int t = tid; t < 16 * 128; t += 256) {
        xt[t >> 7][t & 127] = X[e0 * 128 + t];
    }
    __syncthreads();
    int j = tid & 127;
    int half = tid >> 7;
    float acc[8] = {0, 0, 0, 0, 0, 0, 0, 0};
    for (int k = 0; k < 128; k += 4) {
        float w0 = Wt[k][j], w1 = Wt[k + 1][j], w2 = Wt[k + 2][j], w3 = Wt[k + 3][j];
#pragma unroll
        for (int el = 0; el < 8; ++el) {
            const float4 x4 = *reinterpret_cast<const float4*>(&xt[half * 8 + el][k]);
            acc[el] += x4.x * w0;
            acc[el] += x4.y * w1;
            acc[el] += x4.z * w2;
            acc[el] += x4.w * w3;
        }
    }
#pragma unroll
    for (int el = 0; el < 8; ++el) {
        Y[(e0 + half * 8 + el) * 128 + j] = acc[el];
    }
    if (WITH_A) {
        float av = att[j];
        float contrib[8];
#pragma unroll
        for (int el = 0; el < 8; ++el) contrib[el] = acc[el] * av;
#pragma unroll
        for (int off = 32; off > 0; off >>= 1) {
#pragma unroll
            for (int el = 0; el < 8; ++el)
                contrib[el] += __shfl_xor(contrib[el], off, 64);
        }
        int lane = tid & 63, wave = tid >> 6;
        if (lane == 0) {
#pragma unroll
            for (int el = 0; el < 8; ++el) ared[wave][el] = contrib[el];
        }
        __syncthreads();
        if (tid < 16) {
            int hh = tid >> 3, el = tid & 7;
            a_out[blockIdx.x * 16 + hh * 8 + el] = ared[hh * 2][el] + ared[hh * 2 + 1][el];
        }
    }
}

// ---------------------------------------------------------------------------
// K4: softmax over the edge axis per (b,d), then T = attn * agg (in place over S).
// One block per b, 1024 threads = (d = tid&127, ys = tid>>7 in 0..7).
// ---------------------------------------------------------------------------
__global__ __launch_bounds__(1024) void k_softmax_mul(const float* __restrict__ S,
                                                      const float* __restrict__ agg,
                                                      float* __restrict__ T) {
    int b = blockIdx.x;
    int d = threadIdx.x & 127, ys = threadIdx.x >> 7;
    const float* Sb = S + (long)b * EE * DD;
    const float* Ab = agg + (long)b * EE * DD;
    float* Tb = T + (long)b * EE * DD;
    __shared__ float red[8][128];
    __shared__ float smax[128], rinv[128];
    float m = -INFINITY;
    for (int e = ys; e < EE; e += 8) m = fmaxf(m, Sb[e * DD + d]);
    red[ys][d] = m;
    __syncthreads();
    if (ys == 0) {
        float mm = red[0][d];
#pragma unroll
        for (int i = 1; i < 8; ++i) mm = fmaxf(mm, red[i][d]);
        smax[d] = mm;
    }
    __syncthreads();
    float mm = smax[d];
    float s = 0.0f;
    for (int e = ys; e < EE; e += 8) s += __expf(Sb[e * DD + d] - mm);
    red[ys][d] = s;
    __syncthreads();
    if (ys == 0) {
        float ss = red[0][d];
#pragma unroll
        for (int i = 1; i < 8; ++i) ss += red[i][d];
        rinv[d] = 1.0f / ss;
    }
    __syncthreads();
    float ri = rinv[d];
    for (int e = ys; e < EE; e += 8) {
        long off = (long)e * DD + d;
        Tb[off] = __expf(Sb[off] - mm) * ri * Ab[off];
    }
}

// ---------------------------------------------------------------------------
// K6: per-batch tail: softmax over a[b,:], pooled = sum_e w_e * ef[b,e,:],
// out = pooled @ ec_proj_w^T + b, logits = out @ fc_w^T + fc_b.
// One block of 256 threads per batch.
// ---------------------------------------------------------------------------
__global__ __launch_bounds__(256) void k_final(const float* __restrict__ ef,
                                               const float* __restrict__ abuf,
                                               const float* __restrict__ ec_proj_w,
                                               const float* __restrict__ ec_proj_b,
                                               const float* __restrict__ fc_w,
                                               const float* __restrict__ fc_b,
                                               float* __restrict__ out) {
    int b = blockIdx.x;
    int tid = threadIdx.x;
    __shared__ float wgt[EE];
    __shared__ float red[256];
    __shared__ float pooled[DD];
    __shared__ float outv[DD];
    const float* ab = abuf + b * EE;
    float4 av4 = reinterpret_cast<const float4*>(ab)[tid];
    float av[4] = {av4.x, av4.y, av4.z, av4.w};
    float lm = fmaxf(fmaxf(av[0], av[1]), fmaxf(av[2], av[3]));
    red[tid] = lm;
    __syncthreads();
    for (int s = 128; s > 0; s >>= 1) {
        if (tid < s) red[tid] = fmaxf(red[tid], red[tid + s]);
        __syncthreads();
    }
    float gm = red[0];
    __syncthreads();
    float ls = 0.0f;
#pragma unroll
    for (int i = 0; i < 4; ++i) { av[i] = __expf(av[i] - gm); ls += av[i]; }
    red[tid] = ls;
    __syncthreads();
    for (int s = 128; s > 0; s >>= 1) {
        if (tid < s) red[tid] += red[tid + s];
        __syncthreads();
    }
    float ri = 1.0f / red[0];
    __syncthreads();
#pragma unroll
    for (int i = 0; i < 4; ++i) wgt[tid * 4 + i] = av[i] * ri;
    __syncthreads();
    // pooled[d] = sum_e wgt[e] * ef[b,e,d]
    int d = tid & 127, ys = tid >> 7;
    const float* efb = ef + (long)b * EE * DD;
    float pacc = 0.0f;
    for (int e = ys; e < EE; e += 2) pacc += wgt[e] * efb[e * DD + d];
    red[tid] = pacc;
    __syncthreads();
    if (ys == 0) pooled[d] = red[d] + red[128 + d];
    __syncthreads();
    if (tid < 128) {
        float o = ec_proj_b[tid];
        const float* wr = ec_proj_w + tid * 128;
        for (int k = 0; k < 128; ++k) o += pooled[k] * wr[k];
        outv[tid] = o;
    }
    __syncthreads();
    if (tid < NCAT) {
        float o = fc_b[tid];
        const float* wr = fc_w + tid * 128;
        for (int k = 0; k < 128; ++k) o += outv[k] * wr[k];
        out[b * NCAT + tid] = o;
    }
}

// ---------------------------------------------------------------------------
extern "C" void kernel_launch(void* const* d_in, const int* in_sizes, int n_in,
                              void* d_out, int out_size, void* d_ws, size_t ws_size,
                              hipStream_t stream) {
    const float* nf     = (const float*)d_in[0];
    const float* inc    = (const float*)d_in[1];
    const float* W_att  = (const float*)d_in[2];
    const float* W_proj = (const float*)d_in[3];
    const float* ec_att = (const float*)d_in[4];
    const float* ec_pw  = (const float*)d_in[5];
    const float* ec_pb  = (const float*)d_in[6];
    const float* fc_w   = (const float*)d_in[7];
    const float* fc_b   = (const float*)d_in[8];
    float* out = (float*)d_out;

    char* ws = (char*)d_ws;
    int* cnt            = (int*)ws;                               // 32 KB
    unsigned short* lst = (unsigned short*)(ws + 32768);          // 8192*384*2 = 6 MB
    float* agg          = (float*)(ws + 32768 + 8192 * CAP * 2);  // 4 MB
    float* sc           = agg + 8192 * 128;                       // 4 MB (scores, then t in place)
    float* ef           = sc + 8192 * 128;                        // 4 MB
    float* abuf         = ef + 8192 * 128;                        // 32 KB

    hipMemsetAsync(cnt, 0, BB * EE * sizeof(int), stream);
    k_build<<<(BB * MM * EE / 4) / 256, 256, 0, stream>>>(inc, cnt, lst);
    k_agg<<<BB * EE, 128, 0, stream>>>(nf, cnt, lst, agg);
    k_rowgemm<false><<<8192 / 16, 256, 0, stream>>>(agg, W_att, sc, nullptr, nullptr);
    k_softmax_mul<<<BB, 1024, 0, stream>>>(sc, agg, sc);
    k_rowgemm<true><<<8192 / 16, 256, 0, stream>>>(sc, W_proj, ef, ec_att, abuf);
    k_final<<<BB, 256, 0, stream>>>(ef, abuf, ec_pw, ec_pb, fc_w, fc_b, out);
}

// Round 2
// 523.656 us; speedup vs baseline: 1.4346x; 1.4346x over previous
//
#include <hip/hip_runtime.h>

#define BB 8
#define MM 4096
#define EE 1024
#define DD 128
#define NCAT 64
#define MT 32   // m-chunk staged in LDS

// ---------------------------------------------------------------------------
// K1 (new): dense agg[b,e,:] = sum_m inc[b,m,e] * nf[b,m,:]
// One block = 32 edges x 128 d for one (b, m-split). 128 threads:
//   dq = tid&31 -> d0 = dq*4 (4 d per thread)
//   eq = tid>>5 -> e0 = eq*8 (8 e per thread)
// acc[8][4] per thread. nf chunk (32m x 128d, 16KB) + inc chunk (32m x 32e,
// 4KB) staged in LDS. b = blockIdx&7 pins batch b's nf to XCD b's L2.
// Writes partial sums; combined later.
// ---------------------------------------------------------------------------
__global__ __launch_bounds__(128) void k_dagg(const float* __restrict__ nf,
                                              const float* __restrict__ inc,
                                              float* __restrict__ part,
                                              int mlen) {
    int bid = blockIdx.x;                 // b + 8*(et + 32*ms)
    int b  = bid & 7;
    int et = (bid >> 3) & 31;
    int ms = bid >> 8;
    __shared__ float nfs[MT][DD];         // 16 KB
    __shared__ float incs[MT][32];        // 4 KB
    int tid = threadIdx.x;
    int dq = tid & 31;
    int eq = tid >> 5;                    // 0..3
    float acc[8][4];
#pragma unroll
    for (int i = 0; i < 8; ++i)
#pragma unroll
        for (int j = 0; j < 4; ++j) acc[i][j] = 0.0f;

    long mbase = (long)ms * mlen;
    const float* nfp  = nf  + ((long)b * MM + mbase) * DD;
    const float* incp = inc + ((long)b * MM + mbase) * EE + et * 32;

    for (int mc = 0; mc < mlen; mc += MT) {
        // stage nf[mc..mc+32, 0..128): 1024 float4, coalesced
        const float4* s4 = (const float4*)(nfp + (long)mc * DD);
        float4* n4 = (float4*)nfs;
#pragma unroll
        for (int i = 0; i < 8; ++i) n4[tid + 128 * i] = s4[tid + 128 * i];
        // stage inc[mc..mc+32, et*32..et*32+32): 32 rows x 128B
        {
            int r = tid >> 3;             // 0..15
            int c = (tid & 7) * 4;
            *(float4*)&incs[r][c]      = *(const float4*)&incp[(long)(mc + r) * EE + c];
            *(float4*)&incs[r + 16][c] = *(const float4*)&incp[(long)(mc + r + 16) * EE + c];
        }
        __syncthreads();
#pragma unroll 8
        for (int m = 0; m < MT; ++m) {
            float4 xn = *(const float4*)&nfs[m][dq * 4];
            float4 i0 = *(const float4*)&incs[m][eq * 8];
            float4 i1 = *(const float4*)&incs[m][eq * 8 + 4];
            float ev[8] = {i0.x, i0.y, i0.z, i0.w, i1.x, i1.y, i1.z, i1.w};
#pragma unroll
            for (int e = 0; e < 8; ++e) {
                acc[e][0] += ev[e] * xn.x;
                acc[e][1] += ev[e] * xn.y;
                acc[e][2] += ev[e] * xn.z;
                acc[e][3] += ev[e] * xn.w;
            }
        }
        __syncthreads();
    }
    float* pp = part + (long)ms * (BB * (long)EE * DD)
              + ((long)b * EE + et * 32 + eq * 8) * DD + dq * 4;
#pragma unroll
    for (int e = 0; e < 8; ++e) {
        float4 v = make_float4(acc[e][0], acc[e][1], acc[e][2], acc[e][3]);
        *(float4*)(pp + (long)e * DD) = v;
    }
}

// ---------------------------------------------------------------------------
// K3/K5: Y[r,:] = X[r,:] @ W^T for X (8192 x 128), W (128 x 128), fp32.
// X is given as `nparts` partial buffers (stride pstride); the combined row is
// optionally written to aggout (for the softmax kernel). WITH_A additionally
// computes a[r] = Y[r,:] . att (wave shfl reduction).
// ---------------------------------------------------------------------------
template <bool WITH_A>
__global__ __launch_bounds__(256) void k_rowgemm(const float* __restrict__ X,
                                                 int nparts, long pstride,
                                                 float* __restrict__ aggout,
                                                 const float* __restrict__ W,
                                                 float* __restrict__ Y,
                                                 const float* __restrict__ att,
                                                 float* __restrict__ a_out) {
    __shared__ float Wt[128][129];   // Wt[k][j] = W[j][k]
    __shared__ float xt[16][128];
    __shared__ float ared[4][8];
    int tid = threadIdx.x;
    for (int t = tid; t < 128 * 128; t += 256) {
        int j = t >> 7, k = t & 127;
        Wt[k][j] = W[t];
    }
    int e0 = blockIdx.x * 16;
    for (int t = tid; t < 16 * 128; t += 256) {
        long off = (long)e0 * 128 + t;
        float v = X[off];
        for (int p = 1; p < nparts; ++p) v += X[off + (long)p * pstride];
        xt[t >> 7][t & 127] = v;
        if (aggout) aggout[off] = v;
    }
    __syncthreads();
    int j = tid & 127;
    int half = tid >> 7;
    float acc[8] = {0, 0, 0, 0, 0, 0, 0, 0};
    for (int k = 0; k < 128; k += 4) {
        float w0 = Wt[k][j], w1 = Wt[k + 1][j], w2 = Wt[k + 2][j], w3 = Wt[k + 3][j];
#pragma unroll
        for (int el = 0; el < 8; ++el) {
            const float4 x4 = *reinterpret_cast<const float4*>(&xt[half * 8 + el][k]);
            acc[el] += x4.x * w0;
            acc[el] += x4.y * w1;
            acc[el] += x4.z * w2;
            acc[el] += x4.w * w3;
        }
    }
#pragma unroll
    for (int el = 0; el < 8; ++el) {
        Y[(e0 + half * 8 + el) * 128 + j] = acc[el];
    }
    if (WITH_A) {
        float av = att[j];
        float contrib[8];
#pragma unroll
        for (int el = 0; el < 8; ++el) contrib[el] = acc[el] * av;
#pragma unroll
        for (int off = 32; off > 0; off >>= 1) {
#pragma unroll
            for (int el = 0; el < 8; ++el)
                contrib[el] += __shfl_xor(contrib[el], off, 64);
        }
        int lane = tid & 63, wave = tid >> 6;
        if (lane == 0) {
#pragma unroll
            for (int el = 0; el < 8; ++el) ared[wave][el] = contrib[el];
        }
        __syncthreads();
        if (tid < 16) {
            int hh = tid >> 3, el = tid & 7;
            a_out[blockIdx.x * 16 + hh * 8 + el] = ared[hh * 2][el] + ared[hh * 2 + 1][el];
        }
    }
}

// ---------------------------------------------------------------------------
// K4: softmax over the edge axis per (b,d), then T = attn * agg.
// ---------------------------------------------------------------------------
__global__ __launch_bounds__(1024) void k_softmax_mul(const float* __restrict__ S,
                                                      const float* __restrict__ agg,
                                                      float* __restrict__ T) {
    int b = blockIdx.x;
    int d = threadIdx.x & 127, ys = threadIdx.x >> 7;
    const float* Sb = S + (long)b * EE * DD;
    const float* Ab = agg + (long)b * EE * DD;
    float* Tb = T + (long)b * EE * DD;
    __shared__ float red[8][128];
    __shared__ float smax[128], rinv[128];
    float m = -INFINITY;
    for (int e = ys; e < EE; e += 8) m = fmaxf(m, Sb[e * DD + d]);
    red[ys][d] = m;
    __syncthreads();
    if (ys == 0) {
        float mm = red[0][d];
#pragma unroll
        for (int i = 1; i < 8; ++i) mm = fmaxf(mm, red[i][d]);
        smax[d] = mm;
    }
    __syncthreads();
    float mm = smax[d];
    float s = 0.0f;
    for (int e = ys; e < EE; e += 8) s += __expf(Sb[e * DD + d] - mm);
    red[ys][d] = s;
    __syncthreads();
    if (ys == 0) {
        float ss = red[0][d];
#pragma unroll
        for (int i = 1; i < 8; ++i) ss += red[i][d];
        rinv[d] = 1.0f / ss;
    }
    __syncthreads();
    float ri = rinv[d];
    for (int e = ys; e < EE; e += 8) {
        long off = (long)e * DD + d;
        Tb[off] = __expf(Sb[off] - mm) * ri * Ab[off];
    }
}

// ---------------------------------------------------------------------------
// K6: per-batch tail.
// ---------------------------------------------------------------------------
__global__ __launch_bounds__(256) void k_final(const float* __restrict__ ef,
                                               const float* __restrict__ abuf,
                                               const float* __restrict__ ec_proj_w,
                                               const float* __restrict__ ec_proj_b,
                                               const float* __restrict__ fc_w,
                                               const float* __restrict__ fc_b,
                                               float* __restrict__ out) {
    int b = blockIdx.x;
    int tid = threadIdx.x;
    __shared__ float wgt[EE];
    __shared__ float red[256];
    __shared__ float pooled[DD];
    __shared__ float outv[DD];
    const float* ab = abuf + b * EE;
    float4 av4 = reinterpret_cast<const float4*>(ab)[tid];
    float av[4] = {av4.x, av4.y, av4.z, av4.w};
    float lm = fmaxf(fmaxf(av[0], av[1]), fmaxf(av[2], av[3]));
    red[tid] = lm;
    __syncthreads();
    for (int s = 128; s > 0; s >>= 1) {
        if (tid < s) red[tid] = fmaxf(red[tid], red[tid + s]);
        __syncthreads();
    }
    float gm = red[0];
    __syncthreads();
    float ls = 0.0f;
#pragma unroll
    for (int i = 0; i < 4; ++i) { av[i] = __expf(av[i] - gm); ls += av[i]; }
    red[tid] = ls;
    __syncthreads();
    for (int s = 128; s > 0; s >>= 1) {
        if (tid < s) red[tid] += red[tid + s];
        __syncthreads();
    }
    float ri = 1.0f / red[0];
    __syncthreads();
#pragma unroll
    for (int i = 0; i < 4; ++i) wgt[tid * 4 + i] = av[i] * ri;
    __syncthreads();
    int d = tid & 127, ys = tid >> 7;
    const float* efb = ef + (long)b * EE * DD;
    float pacc = 0.0f;
    for (int e = ys; e < EE; e += 2) pacc += wgt[e] * efb[e * DD + d];
    red[tid] = pacc;
    __syncthreads();
    if (ys == 0) pooled[d] = red[d] + red[128 + d];
    __syncthreads();
    if (tid < 128) {
        float o = ec_proj_b[tid];
        const float* wr = ec_proj_w + tid * 128;
        for (int k = 0; k < 128; ++k) o += pooled[k] * wr[k];
        outv[tid] = o;
    }
    __syncthreads();
    if (tid < NCAT) {
        float o = fc_b[tid];
        const float* wr = fc_w + tid * 128;
        for (int k = 0; k < 128; ++k) o += outv[k] * wr[k];
        out[b * NCAT + tid] = o;
    }
}

// ---------------------------------------------------------------------------
extern "C" void kernel_launch(void* const* d_in, const int* in_sizes, int n_in,
                              void* d_out, int out_size, void* d_ws, size_t ws_size,
                              hipStream_t stream) {
    const float* nf     = (const float*)d_in[0];
    const float* inc    = (const float*)d_in[1];
    const float* W_att  = (const float*)d_in[2];
    const float* W_proj = (const float*)d_in[3];
    const float* ec_att = (const float*)d_in[4];
    const float* ec_pw  = (const float*)d_in[5];
    const float* ec_pb  = (const float*)d_in[6];
    const float* fc_w   = (const float*)d_in[7];
    const float* fc_b   = (const float*)d_in[8];
    float* out = (float*)d_out;

    const long NROW = (long)BB * EE;          // 8192
    const long PSTRIDE = NROW * DD;           // floats per partial (4 MB)

    // nsplit=4 needs part 16MB + agg 4MB + sc 4MB + abuf; fall back to 2.
    size_t need4 = (size_t)(4 + 2) * PSTRIDE * 4 + 65536;
    int nsplit = (ws_size >= need4) ? 4 : 2;
    int mlen = MM / nsplit;

    char* ws = (char*)d_ws;
    float* part = (float*)ws;                                  // nsplit * 4 MB
    float* agg  = (float*)(ws + (size_t)nsplit * PSTRIDE * 4); // 4 MB
    float* sc   = agg + PSTRIDE;                               // 4 MB
    float* abuf = sc + PSTRIDE;                                // 32 KB
    float* ef   = (float*)ws;                                  // reuse part region

    k_dagg<<<8 * 32 * nsplit, 128, 0, stream>>>(nf, inc, part, mlen);
    k_rowgemm<false><<<NROW / 16, 256, 0, stream>>>(part, nsplit, PSTRIDE, agg,
                                                    W_att, sc, nullptr, nullptr);
    k_softmax_mul<<<BB, 1024, 0, stream>>>(sc, agg, sc);
    k_rowgemm<true><<<NROW / 16, 256, 0, stream>>>(sc, 1, 0, nullptr,
                                                   W_proj, ef, ec_att, abuf);
    k_final<<<BB, 256, 0, stream>>>(ef, abuf, ec_pw, ec_pb, fc_w, fc_b, out);
}

// Round 3
// 282.528 us; speedup vs baseline: 2.6591x; 1.8535x over previous
//
#include <hip/hip_runtime.h>

#define BB 8
#define MM 4096
#define EE 1024
#define DD 128
#define NCAT 64

typedef __attribute__((ext_vector_type(8))) short bf16x8;
typedef __attribute__((ext_vector_type(4))) float f32x4;

// ---------------------------------------------------------------------------
// K1: agg = inc^T @ nf per batch via bf16 MFMA.
//   C[e][d] = sum_m inc[m][e] * nf[m][d],  A = inc^T (binary -> bf16 EXACT),
//   B = nf split hi/lo bf16 (two MFMAs -> ~fp24 precision).
// Grid 256 = b(8) x et(8: 128-e block) x ks(4: 1024-m split). 1 block/CU.
// Block tile 128e x 128d, 4 waves (2x2), wave tile 64e x 64d = 4x4 frags of
// 16x16x32. LDS subtile layout [kgroup(4)][col(128)][8 shorts]: staging writes
// and frag reads are all 16B, conflict-free. 2-deep register prefetch.
// Writes fp32 partials part[ks]; combined in k_score.
// ---------------------------------------------------------------------------
__global__ __launch_bounds__(256, 1) void k_magg(const float* __restrict__ nf,
                                                 const float* __restrict__ inc,
                                                 float* __restrict__ part) {
    int bid = blockIdx.x;
    int b  = bid & 7;
    int et = (bid >> 3) & 7;
    int ks = bid >> 6;

    __shared__ ushort As2[4][128][8];   // A: [kgrp][e][k-in-grp]  8KB
    __shared__ ushort Bh2[4][128][8];   // B hi: [kgrp][d][k]      8KB
    __shared__ ushort Bl2[4][128][8];   // B lo                     8KB

    int tid  = threadIdx.x;
    int lane = tid & 63;
    int w    = tid >> 6;
    int we   = (w & 1) * 64;
    int wd   = (w >> 1) * 64;

    int ecol = tid & 127;               // staging column (e for A, d for B)
    int mh   = tid >> 7;                // 0..1 -> 16-m half of the 32-m step

    long m0base = (long)ks * 1024;
    const float* incc = inc + ((long)b * MM + m0base + mh * 16) * EE + (et * 128 + ecol);
    const float* nfc  = nf  + ((long)b * MM + m0base + mh * 16) * DD + ecol;

    f32x4 acc[4][4];
#pragma unroll
    for (int i = 0; i < 4; ++i)
#pragma unroll
        for (int j = 0; j < 4; ++j) acc[i][j] = (f32x4)(0.0f);

#define LOADM(ra, rb, t)                                                      \
    do {                                                                      \
        _Pragma("unroll")                                                     \
        for (int j2 = 0; j2 < 16; ++j2) {                                     \
            ra[j2] = incc[(long)((t) * 32 + j2) * EE];                        \
            rb[j2] = nfc[(long)((t) * 32 + j2) * DD];                         \
        }                                                                     \
    } while (0)

#define STOREM(ra, rb)                                                        \
    do {                                                                      \
        uint ua[8], uh[8], ul[8];                                             \
        _Pragma("unroll")                                                     \
        for (int q = 0; q < 8; ++q) {                                         \
            ua[q] = (__float_as_uint(ra[2 * q]) >> 16) |                      \
                    (__float_as_uint(ra[2 * q + 1]) & 0xffff0000u);           \
            float x0 = rb[2 * q], x1 = rb[2 * q + 1];                         \
            uint h0 = __float_as_uint(x0) & 0xffff0000u;                      \
            uint h1 = __float_as_uint(x1) & 0xffff0000u;                      \
            uh[q] = (h0 >> 16) | h1;                                          \
            float l0 = x0 - __uint_as_float(h0);                              \
            float l1 = x1 - __uint_as_float(h1);                              \
            ul[q] = (__float_as_uint(l0) >> 16) |                             \
                    (__float_as_uint(l1) & 0xffff0000u);                      \
        }                                                                     \
        *(uint4*)&As2[2 * mh][ecol][0]     = make_uint4(ua[0], ua[1], ua[2], ua[3]); \
        *(uint4*)&As2[2 * mh + 1][ecol][0] = make_uint4(ua[4], ua[5], ua[6], ua[7]); \
        *(uint4*)&Bh2[2 * mh][ecol][0]     = make_uint4(uh[0], uh[1], uh[2], uh[3]); \
        *(uint4*)&Bh2[2 * mh + 1][ecol][0] = make_uint4(uh[4], uh[5], uh[6], uh[7]); \
        *(uint4*)&Bl2[2 * mh][ecol][0]     = make_uint4(ul[0], ul[1], ul[2], ul[3]); \
        *(uint4*)&Bl2[2 * mh + 1][ecol][0] = make_uint4(ul[4], ul[5], ul[6], ul[7]); \
    } while (0)

#define COMPUTEM()                                                            \
    do {                                                                      \
        int kg = lane >> 4, rr = lane & 15;                                   \
        bf16x8 af[4];                                                         \
        _Pragma("unroll")                                                     \
        for (int i = 0; i < 4; ++i)                                           \
            af[i] = *(const bf16x8*)&As2[kg][we + i * 16 + rr][0];            \
        _Pragma("unroll")                                                     \
        for (int j = 0; j < 4; ++j) {                                         \
            bf16x8 bh = *(const bf16x8*)&Bh2[kg][wd + j * 16 + rr][0];        \
            bf16x8 bl = *(const bf16x8*)&Bl2[kg][wd + j * 16 + rr][0];        \
            _Pragma("unroll")                                                 \
            for (int i = 0; i < 4; ++i) {                                     \
                acc[i][j] = __builtin_amdgcn_mfma_f32_16x16x32_bf16(af[i], bh, acc[i][j], 0, 0, 0); \
                acc[i][j] = __builtin_amdgcn_mfma_f32_16x16x32_bf16(af[i], bl, acc[i][j], 0, 0, 0); \
            }                                                                 \
        }                                                                     \
    } while (0)

    float a0[16], b0[16], a1[16], b1[16];
    LOADM(a0, b0, 0);
    LOADM(a1, b1, 1);
    const int NT = 32;                   // 1024 m / 32 per step
    for (int t = 0; t < NT; t += 2) {
        STOREM(a0, b0);
        __syncthreads();
        if (t + 2 < NT) LOADM(a0, b0, t + 2);
        COMPUTEM();
        __syncthreads();
        STOREM(a1, b1);
        __syncthreads();
        if (t + 3 < NT) LOADM(a1, b1, t + 3);
        COMPUTEM();
        __syncthreads();
    }

    float* pp = part + (long)ks * ((long)BB * EE * DD) + ((long)b * EE + et * 128) * DD;
#pragma unroll
    for (int i = 0; i < 4; ++i)
#pragma unroll
        for (int j = 0; j < 4; ++j) {
            int e = we + i * 16 + ((lane >> 4) << 2);
            int d = wd + j * 16 + (lane & 15);
#pragma unroll
            for (int r = 0; r < 4; ++r)
                pp[(long)(e + r) * DD + d] = acc[i][j][r];
        }
#undef LOADM
#undef STOREM
#undef COMPUTEM
}

// ---------------------------------------------------------------------------
// K2: combine 4 k-split partials -> agg; scores = agg @ W_att^T -> sc.
// ---------------------------------------------------------------------------
__global__ __launch_bounds__(256) void k_score(const float* __restrict__ part,
                                               float* __restrict__ agg,
                                               const float* __restrict__ W,
                                               float* __restrict__ Y) {
    __shared__ float Wt[128][129];
    __shared__ float xt[16][128];
    int tid = threadIdx.x;
    for (int t = tid; t < 128 * 128; t += 256) Wt[t & 127][t >> 7] = W[t];
    long r0 = (long)blockIdx.x * 16;
    const long PS = (long)BB * EE * DD;
    for (int t = tid; t < 2048; t += 256) {
        long off = r0 * 128 + t;
        float v = part[off] + part[off + PS] + part[off + 2 * PS] + part[off + 3 * PS];
        xt[t >> 7][t & 127] = v;
        agg[off] = v;
    }
    __syncthreads();
    int j = tid & 127, half = tid >> 7;
    float acc[8] = {0, 0, 0, 0, 0, 0, 0, 0};
    for (int k = 0; k < 128; k += 4) {
        float w0 = Wt[k][j], w1 = Wt[k + 1][j], w2 = Wt[k + 2][j], w3 = Wt[k + 3][j];
#pragma unroll
        for (int el = 0; el < 8; ++el) {
            float4 x4 = *(const float4*)&xt[half * 8 + el][k];
            acc[el] += x4.x * w0; acc[el] += x4.y * w1;
            acc[el] += x4.z * w2; acc[el] += x4.w * w3;
        }
    }
#pragma unroll
    for (int el = 0; el < 8; ++el) Y[(r0 + half * 8 + el) * 128 + j] = acc[el];
}

// ---------------------------------------------------------------------------
// K3: column sum of exp(scores) over e per (b,d). No max subtraction
// (|score| <~ 45, exp fits fp32 with huge headroom). Grid 8b x 16 chunks.
// ---------------------------------------------------------------------------
__global__ __launch_bounds__(256) void k_colsum(const float* __restrict__ S,
                                                float* __restrict__ colsum) {
    int b = blockIdx.x & 7, ch = blockIdx.x >> 3;
    int d = threadIdx.x & 127, eh = threadIdx.x >> 7;
    const float* Sb = S + ((long)b * EE + ch * 64) * DD + d;
    float s = 0.0f;
    for (int e = eh; e < 64; e += 2) s += __expf(Sb[(long)e * DD]);
    atomicAdd(&colsum[b * DD + d], s);
}

// ---------------------------------------------------------------------------
// K4: ef = (exp(S)*rinv*agg) @ W_proj^T  (softmax-multiply fused into X-load);
// also a[r] = ef[r,:] . ec_att -> abuf = exp(a), sumA += sum(exp(a)).
// ---------------------------------------------------------------------------
__global__ __launch_bounds__(256) void k_proj(const float* __restrict__ S,
                                              const float* __restrict__ agg,
                                              const float* __restrict__ colsum,
                                              const float* __restrict__ W,
                                              float* __restrict__ Y,
                                              const float* __restrict__ att,
                                              float* __restrict__ abuf,
                                              float* __restrict__ sumA) {
    __shared__ float Wt[128][129];
    __shared__ float xt[16][128];
    __shared__ float ared[4][8];
    __shared__ float aex[16];
    int tid = threadIdx.x;
    for (int t = tid; t < 128 * 128; t += 256) Wt[t & 127][t >> 7] = W[t];
    long r0 = (long)blockIdx.x * 16;
    int b = (int)(r0 >> 10);
    float rinv = 1.0f / colsum[b * DD + (tid & 127)];
    for (int t = tid; t < 2048; t += 256) {
        long off = r0 * 128 + t;
        xt[t >> 7][t & 127] = __expf(S[off]) * rinv * agg[off];
    }
    __syncthreads();
    int j = tid & 127, half = tid >> 7;
    float acc[8] = {0, 0, 0, 0, 0, 0, 0, 0};
    for (int k = 0; k < 128; k += 4) {
        float w0 = Wt[k][j], w1 = Wt[k + 1][j], w2 = Wt[k + 2][j], w3 = Wt[k + 3][j];
#pragma unroll
        for (int el = 0; el < 8; ++el) {
            float4 x4 = *(const float4*)&xt[half * 8 + el][k];
            acc[el] += x4.x * w0; acc[el] += x4.y * w1;
            acc[el] += x4.z * w2; acc[el] += x4.w * w3;
        }
    }
#pragma unroll
    for (int el = 0; el < 8; ++el) Y[(r0 + half * 8 + el) * 128 + j] = acc[el];
    // a-row dot with att
    float av = att[j];
    float contrib[8];
#pragma unroll
    for (int el = 0; el < 8; ++el) contrib[el] = acc[el] * av;
#pragma unroll
    for (int off2 = 32; off2 > 0; off2 >>= 1)
#pragma unroll
        for (int el = 0; el < 8; ++el) contrib[el] += __shfl_xor(contrib[el], off2, 64);
    int lane = tid & 63, wv = tid >> 6;
    if (lane == 0)
#pragma unroll
        for (int el = 0; el < 8; ++el) ared[wv][el] = contrib[el];
    __syncthreads();
    if (tid < 16) {
        int hh = tid >> 3, el = tid & 7;
        float a = ared[hh * 2][el] + ared[hh * 2 + 1][el];
        float ea = __expf(a);
        abuf[r0 + tid] = ea;
        aex[tid] = ea;
    }
    __syncthreads();
    if (tid == 0) {
        float s2 = 0.0f;
#pragma unroll
        for (int i = 0; i < 16; ++i) s2 += aex[i];
        atomicAdd(&sumA[b], s2);
    }
}

// ---------------------------------------------------------------------------
// K5: praw[b][d] = sum_e exp(a_e) * ef[b,e,d]   (rinv applied in k_out)
// ---------------------------------------------------------------------------
__global__ __launch_bounds__(256) void k_pool(const float* __restrict__ ef,
                                              const float* __restrict__ abuf,
                                              float* __restrict__ praw) {
    int b = blockIdx.x & 7, ch = blockIdx.x >> 3;
    int d = threadIdx.x & 127, eh = threadIdx.x >> 7;
    const float* efb = ef + ((long)b * EE + ch * 64) * DD + d;
    const float* ab = abuf + b * EE + ch * 64;
    float s = 0.0f;
    for (int e = eh; e < 64; e += 2) s += ab[e] * efb[(long)e * DD];
    atomicAdd(&praw[b * DD + d], s);
}

// ---------------------------------------------------------------------------
// K6: pooled = praw * (1/sumA); out = pooled@ec_pw^T + b; logits = out@fc^T + fc_b
// ---------------------------------------------------------------------------
__global__ __launch_bounds__(128) void k_out(const float* __restrict__ praw,
                                             const float* __restrict__ sumA,
                                             const float* __restrict__ ec_pw,
                                             const float* __restrict__ ec_pb,
                                             const float* __restrict__ fc_w,
                                             const float* __restrict__ fc_b,
                                             float* __restrict__ out) {
    int b = blockIdx.x, tid = threadIdx.x;
    __shared__ float pooled[DD];
    __shared__ float outv[DD];
    float rinv = 1.0f / sumA[b];
    pooled[tid] = praw[b * DD + tid] * rinv;
    __syncthreads();
    float o = ec_pb[tid];
    const float* wr = ec_pw + tid * DD;
    for (int k = 0; k < DD; ++k) o += pooled[k] * wr[k];
    outv[tid] = o;
    __syncthreads();
    if (tid < NCAT) {
        float o2 = fc_b[tid];
        const float* wr2 = fc_w + tid * DD;
        for (int k = 0; k < DD; ++k) o2 += outv[k] * wr2[k];
        out[b * NCAT + tid] = o2;
    }
}

// ---------------------------------------------------------------------------
extern "C" void kernel_launch(void* const* d_in, const int* in_sizes, int n_in,
                              void* d_out, int out_size, void* d_ws, size_t ws_size,
                              hipStream_t stream) {
    const float* nf     = (const float*)d_in[0];
    const float* inc    = (const float*)d_in[1];
    const float* W_att  = (const float*)d_in[2];
    const float* W_proj = (const float*)d_in[3];
    const float* ec_att = (const float*)d_in[4];
    const float* ec_pw  = (const float*)d_in[5];
    const float* ec_pb  = (const float*)d_in[6];
    const float* fc_w   = (const float*)d_in[7];
    const float* fc_b   = (const float*)d_in[8];
    float* out = (float*)d_out;

    const long PS = (long)BB * EE * DD;        // 1M floats = 4MB
    char* ws = (char*)d_ws;
    float* part   = (float*)ws;                              // 16 MB (4 splits)
    float* agg    = (float*)(ws + 4 * PS * 4);               // 4 MB
    float* sc     = agg + PS;                                // 4 MB
    float* stats  = sc + PS;                                 // colsum|praw|sumA
    float* colsum = stats;                                   // 1024 f
    float* praw   = stats + 1024;                            // 1024 f
    float* sumA   = stats + 2048;                            // 8 f
    float* abuf   = stats + 2056;                            // 8192 f
    float* ef     = part;                                    // reuse (part dead after k_score)

    hipMemsetAsync(stats, 0, (2048 + 8) * sizeof(float), stream);
    k_magg<<<256, 256, 0, stream>>>(nf, inc, part);
    k_score<<<(BB * EE) / 16, 256, 0, stream>>>(part, agg, W_att, sc);
    k_colsum<<<BB * 16, 256, 0, stream>>>(sc, colsum);
    k_proj<<<(BB * EE) / 16, 256, 0, stream>>>(sc, agg, colsum, W_proj, ef, ec_att, abuf, sumA);
    k_pool<<<BB * 16, 256, 0, stream>>>(ef, abuf, praw);
    k_out<<<BB, 128, 0, stream>>>(praw, sumA, ec_pw, ec_pb, fc_w, fc_b, out);
}

// Round 4
// 265.119 us; speedup vs baseline: 2.8337x; 1.0657x over previous
//
#include <hip/hip_runtime.h>

#define BB 8
#define MM 4096
#define EE 1024
#define DD 128
#define NCAT 64

typedef __attribute__((ext_vector_type(8))) short bf16x8;
typedef __attribute__((ext_vector_type(4))) float f32x4;

// pack two f32 -> (bf16(hi)<<16)|bf16(lo), truncation, 1 instr (v_perm_b32)
__device__ __forceinline__ unsigned pk(float lo, float hi) {
    return __builtin_amdgcn_perm(__float_as_uint(hi), __float_as_uint(lo), 0x07060302u);
}

// ---------------------------------------------------------------------------
// K1: agg = inc^T @ nf per batch via bf16 MFMA (inc binary -> bf16 exact;
// nf split hi/lo bf16 -> ~fp24). Block tile 64e x 128d, 4 waves (2x2),
// wave tile 32e x 64d = 2x4 frags of 16x16x32. Grid 512 = b8 x et16 x ks4,
// >=2 blocks/CU for phase overlap + HBM latency hiding. LDS subtile layout
// [kgrp][col][8 shorts]: all staging writes / frag reads are 16B,
// conflict-free. 1-deep register prefetch (loads for t+1 in flight across
// the compute of t). Writes fp32 partials part[ks]; combined in k_score.
// ---------------------------------------------------------------------------
__global__ __launch_bounds__(256, 2) void k_magg(const float* __restrict__ nf,
                                                 const float* __restrict__ inc,
                                                 float* __restrict__ part) {
    int bid = blockIdx.x;               // b + 8*(et + 16*ks)
    int b  = bid & 7;
    int et = (bid >> 3) & 15;
    int ks = bid >> 7;

    __shared__ __align__(16) unsigned short As[4][64][8];    // 4 KB
    __shared__ __align__(16) unsigned short Bh[4][128][8];   // 8 KB
    __shared__ __align__(16) unsigned short Bl[4][128][8];   // 8 KB

    int tid  = threadIdx.x;
    int lane = tid & 63;
    int w    = tid >> 6;
    int we   = (w & 1) * 32;
    int wd   = (w >> 1) * 64;

    int ecolA = tid & 63;               // e column staged by this thread
    int mgrpA = tid >> 6;               // 0..3 -> 8-m group (= kgroup)
    int dcolB = tid & 127;              // d column staged
    int mhB   = tid >> 7;               // 0..1 -> 16-m half (= 2 kgroups)

    long m0 = (long)ks * 1024;
    const float* incp = inc + ((long)b * MM + m0) * EE + et * 64 + ecolA;
    const float* nfp  = nf  + ((long)b * MM + m0) * DD + dcolB;

    f32x4 acc[2][4];
#pragma unroll
    for (int i = 0; i < 2; ++i)
#pragma unroll
        for (int j = 0; j < 4; ++j) acc[i][j] = (f32x4)(0.0f);

    float ra[8], rb[16];

#define LOADM(t) do {                                                         \
    _Pragma("unroll")                                                         \
    for (int j2 = 0; j2 < 8; ++j2)                                            \
        ra[j2] = incp[(long)((t) * 32 + mgrpA * 8 + j2) * EE];                \
    _Pragma("unroll")                                                         \
    for (int j2 = 0; j2 < 16; ++j2)                                           \
        rb[j2] = nfp[(long)((t) * 32 + mhB * 16 + j2) * DD];                  \
} while (0)

#define STOREM() do {                                                         \
    unsigned ua[4];                                                           \
    _Pragma("unroll")                                                         \
    for (int q = 0; q < 4; ++q) ua[q] = pk(ra[2 * q], ra[2 * q + 1]);         \
    *(uint4*)&As[mgrpA][ecolA][0] = make_uint4(ua[0], ua[1], ua[2], ua[3]);   \
    unsigned uh[8], ul[8];                                                    \
    _Pragma("unroll")                                                         \
    for (int q = 0; q < 8; ++q) {                                             \
        float x0 = rb[2 * q], x1 = rb[2 * q + 1];                             \
        uh[q] = pk(x0, x1);                                                   \
        float h0 = __uint_as_float(__float_as_uint(x0) & 0xffff0000u);        \
        float h1 = __uint_as_float(__float_as_uint(x1) & 0xffff0000u);        \
        ul[q] = pk(x0 - h0, x1 - h1);                                         \
    }                                                                         \
    *(uint4*)&Bh[2 * mhB][dcolB][0]     = make_uint4(uh[0], uh[1], uh[2], uh[3]); \
    *(uint4*)&Bh[2 * mhB + 1][dcolB][0] = make_uint4(uh[4], uh[5], uh[6], uh[7]); \
    *(uint4*)&Bl[2 * mhB][dcolB][0]     = make_uint4(ul[0], ul[1], ul[2], ul[3]); \
    *(uint4*)&Bl[2 * mhB + 1][dcolB][0] = make_uint4(ul[4], ul[5], ul[6], ul[7]); \
} while (0)

    LOADM(0);
    for (int t = 0; t < 32; ++t) {
        STOREM();
        if (t + 1 < 32) LOADM(t + 1);   // in flight across compute of t
        __syncthreads();
        {
            int kg = lane >> 4, rr = lane & 15;
            bf16x8 af[2];
#pragma unroll
            for (int i = 0; i < 2; ++i)
                af[i] = *(const bf16x8*)&As[kg][we + i * 16 + rr][0];
#pragma unroll
            for (int j = 0; j < 4; ++j) {
                bf16x8 bh = *(const bf16x8*)&Bh[kg][wd + j * 16 + rr][0];
                bf16x8 bl = *(const bf16x8*)&Bl[kg][wd + j * 16 + rr][0];
#pragma unroll
                for (int i = 0; i < 2; ++i) {
                    acc[i][j] = __builtin_amdgcn_mfma_f32_16x16x32_bf16(af[i], bh, acc[i][j], 0, 0, 0);
                    acc[i][j] = __builtin_amdgcn_mfma_f32_16x16x32_bf16(af[i], bl, acc[i][j], 0, 0, 0);
                }
            }
        }
        __syncthreads();
    }

    const long PS = (long)BB * EE * DD;
    float* pp = part + (long)ks * PS + ((long)b * EE + et * 64) * DD;
#pragma unroll
    for (int i = 0; i < 2; ++i)
#pragma unroll
        for (int j = 0; j < 4; ++j) {
            int e = we + i * 16 + ((lane >> 4) << 2);
            int d = wd + j * 16 + (lane & 15);
#pragma unroll
            for (int r = 0; r < 4; ++r)
                pp[(long)(e + r) * DD + d] = acc[i][j][r];
        }
#undef LOADM
#undef STOREM
}

// ---------------------------------------------------------------------------
// K2: combine 4 k-split partials -> agg; esc = exp(agg @ W_att^T); fused
// column-sum: colsum[b][d] += sum_{e in block} esc. No max subtraction
// (|score| <~ 45 -> exp fits fp32 with huge headroom).
// ---------------------------------------------------------------------------
__global__ __launch_bounds__(256) void k_score(const float* __restrict__ part,
                                               float* __restrict__ agg,
                                               const float* __restrict__ W,
                                               float* __restrict__ esc,
                                               float* __restrict__ colsum) {
    __shared__ float Wt[128][129];
    __shared__ float xt[16][128];
    __shared__ float cred[2][128];
    int tid = threadIdx.x;
    for (int t = tid; t < 128 * 128; t += 256) Wt[t & 127][t >> 7] = W[t];
    long r0 = (long)blockIdx.x * 16;
    const long PS = (long)BB * EE * DD;
    for (int t = tid; t < 2048; t += 256) {
        long off = r0 * 128 + t;
        float v = part[off] + part[off + PS] + part[off + 2 * PS] + part[off + 3 * PS];
        xt[t >> 7][t & 127] = v;
        agg[off] = v;
    }
    __syncthreads();
    int j = tid & 127, half = tid >> 7;
    float acc[8] = {0, 0, 0, 0, 0, 0, 0, 0};
    for (int k = 0; k < 128; k += 4) {
        float w0 = Wt[k][j], w1 = Wt[k + 1][j], w2 = Wt[k + 2][j], w3 = Wt[k + 3][j];
#pragma unroll
        for (int el = 0; el < 8; ++el) {
            float4 x4 = *(const float4*)&xt[half * 8 + el][k];
            acc[el] += x4.x * w0; acc[el] += x4.y * w1;
            acc[el] += x4.z * w2; acc[el] += x4.w * w3;
        }
    }
    float csum = 0.0f;
#pragma unroll
    for (int el = 0; el < 8; ++el) {
        float es = __expf(acc[el]);
        esc[(r0 + half * 8 + el) * 128 + j] = es;
        csum += es;
    }
    cred[half][j] = csum;
    __syncthreads();
    if (half == 0) {
        int b = (int)(r0 >> 10);
        atomicAdd(&colsum[b * DD + j], cred[0][j] + cred[1][j]);
    }
}

// ---------------------------------------------------------------------------
// K3: ef-rows = (esc*rinv*agg) @ W_proj^T computed in registers only (never
// stored); a_r = ef_r . ec_att -> ea = exp(a_r); fused pooling:
// praw[b][d] += sum_r ea_r * ef[r][d], sumA[b] += sum_r ea_r.
// ---------------------------------------------------------------------------
__global__ __launch_bounds__(256) void k_proj(const float* __restrict__ esc,
                                              const float* __restrict__ agg,
                                              const float* __restrict__ colsum,
                                              const float* __restrict__ W,
                                              const float* __restrict__ att,
                                              float* __restrict__ praw,
                                              float* __restrict__ sumA) {
    __shared__ float Wt[128][129];
    __shared__ float xt[16][128];
    __shared__ float ared[4][8];
    __shared__ float aex[16];
    __shared__ float pred[2][128];
    int tid = threadIdx.x;
    for (int t = tid; t < 128 * 128; t += 256) Wt[t & 127][t >> 7] = W[t];
    long r0 = (long)blockIdx.x * 16;
    int b = (int)(r0 >> 10);
    float rinv = 1.0f / colsum[b * DD + (tid & 127)];
    for (int t = tid; t < 2048; t += 256) {
        long off = r0 * 128 + t;
        xt[t >> 7][t & 127] = esc[off] * rinv * agg[off];
    }
    __syncthreads();
    int j = tid & 127, half = tid >> 7;
    float acc[8] = {0, 0, 0, 0, 0, 0, 0, 0};
    for (int k = 0; k < 128; k += 4) {
        float w0 = Wt[k][j], w1 = Wt[k + 1][j], w2 = Wt[k + 2][j], w3 = Wt[k + 3][j];
#pragma unroll
        for (int el = 0; el < 8; ++el) {
            float4 x4 = *(const float4*)&xt[half * 8 + el][k];
            acc[el] += x4.x * w0; acc[el] += x4.y * w1;
            acc[el] += x4.z * w2; acc[el] += x4.w * w3;
        }
    }
    // a_r = sum_j ef[r][j] * att[j]
    float av = att[j];
    float contrib[8];
#pragma unroll
    for (int el = 0; el < 8; ++el) contrib[el] = acc[el] * av;
#pragma unroll
    for (int off2 = 32; off2 > 0; off2 >>= 1)
#pragma unroll
        for (int el = 0; el < 8; ++el)
            contrib[el] += __shfl_xor(contrib[el], off2, 64);
    int lane = tid & 63, wv = tid >> 6;
    if (lane == 0)
#pragma unroll
        for (int el = 0; el < 8; ++el) ared[wv][el] = contrib[el];
    __syncthreads();
    if (tid < 16) {
        int hh = tid >> 3, el = tid & 7;
        aex[tid] = __expf(ared[hh * 2][el] + ared[hh * 2 + 1][el]);
    }
    __syncthreads();
    if (tid == 0) {
        float s = 0.0f;
#pragma unroll
        for (int i = 0; i < 16; ++i) s += aex[i];
        atomicAdd(&sumA[b], s);
    }
    float p = 0.0f;
#pragma unroll
    for (int el = 0; el < 8; ++el) p += aex[half * 8 + el] * acc[el];
    pred[half][j] = p;
    __syncthreads();
    if (half == 0) atomicAdd(&praw[b * DD + j], pred[0][j] + pred[1][j]);
}

// ---------------------------------------------------------------------------
// K4: pooled = praw/sumA; out = pooled@ec_pw^T + b; logits = out@fc^T + fc_b
// ---------------------------------------------------------------------------
__global__ __launch_bounds__(128) void k_out(const float* __restrict__ praw,
                                             const float* __restrict__ sumA,
                                             const float* __restrict__ ec_pw,
                                             const float* __restrict__ ec_pb,
                                             const float* __restrict__ fc_w,
                                             const float* __restrict__ fc_b,
                                             float* __restrict__ out) {
    int b = blockIdx.x, tid = threadIdx.x;
    __shared__ float pooled[DD];
    __shared__ float outv[DD];
    float rinv = 1.0f / sumA[b];
    pooled[tid] = praw[b * DD + tid] * rinv;
    __syncthreads();
    float o = ec_pb[tid];
    const float* wr = ec_pw + tid * DD;
    for (int k = 0; k < DD; ++k) o += pooled[k] * wr[k];
    outv[tid] = o;
    __syncthreads();
    if (tid < NCAT) {
        float o2 = fc_b[tid];
        const float* wr2 = fc_w + tid * DD;
        for (int k = 0; k < DD; ++k) o2 += outv[k] * wr2[k];
        out[b * NCAT + tid] = o2;
    }
}

// ---------------------------------------------------------------------------
extern "C" void kernel_launch(void* const* d_in, const int* in_sizes, int n_in,
                              void* d_out, int out_size, void* d_ws, size_t ws_size,
                              hipStream_t stream) {
    const float* nf     = (const float*)d_in[0];
    const float* inc    = (const float*)d_in[1];
    const float* W_att  = (const float*)d_in[2];
    const float* W_proj = (const float*)d_in[3];
    const float* ec_att = (const float*)d_in[4];
    const float* ec_pw  = (const float*)d_in[5];
    const float* ec_pb  = (const float*)d_in[6];
    const float* fc_w   = (const float*)d_in[7];
    const float* fc_b   = (const float*)d_in[8];
    float* out = (float*)d_out;

    const long PS = (long)BB * EE * DD;                      // 1M floats
    char* ws = (char*)d_ws;
    float* part   = (float*)ws;                              // 16 MB (4 k-splits)
    float* agg    = (float*)(ws + 4 * PS * 4);               // 4 MB
    float* esc    = agg + PS;                                // 4 MB
    float* stats  = esc + PS;
    float* colsum = stats;                                   // 1024 f
    float* praw   = stats + 1024;                            // 1024 f
    float* sumA   = stats + 2048;                            // 8 f

    hipMemsetAsync(stats, 0, (2048 + 8) * sizeof(float), stream);
    k_magg<<<512, 256, 0, stream>>>(nf, inc, part);
    k_score<<<(BB * EE) / 16, 256, 0, stream>>>(part, agg, W_att, esc, colsum);
    k_proj<<<(BB * EE) / 16, 256, 0, stream>>>(esc, agg, colsum, W_proj, ec_att, praw, sumA);
    k_out<<<BB, 128, 0, stream>>>(praw, sumA, ec_pw, ec_pb, fc_w, fc_b, out);
}